// Round 2
// baseline (295.598 us; speedup 1.0000x reference)
//
#include <hip/hip_runtime.h>

// AdditiveAttention: B=4, Q=256, K=1024, DQ=DK=DV=512, H=128
#define B_ 4
#define Q_ 256
#define K_ 1024
#define D_ 512
#define H_ 128
#define DV_ 512
#define LOG2E 1.4426950408889634f

// tanh via exp2: tanh(x) = 1 - 2/(1+e^{2x}).  The constant term SUM_h w_h
// cancels in softmax, so  p = exp2( SUM_h (-2*log2e*w_h) * rcp(1 + exp2(sc)) )
// with sc = 2*log2e*(qh+kh).  2*log2e is folded into the staged W values in
// proj_part; -2*log2e into w_v at attn staging.  3 VALU + 2 trans / element.
//
// Round-2 structure: proj_part atomicAdds d-slice partials straight into
// qh_s/kh4 (zeroed by a 2.6 MB hipMemsetAsync; destination is L2-resident,
// killing the 21 MB psum write + 21 MB read and the proj_reduce launch).
// attn_part uses 128-k chunks (kc 0..7): half the blocks, half the o_part
// round-trip (16->8 MB each way), same ALU totals.

// ---------------------------------------------------------------------------
// proj_part: one (64-row tile, 64-d slice). Grid 640 = [ds:8 == bid&7][tile:80].
// LDS 51 KB -> 3 blocks/CU. 4 waves = (32r x 64h) quadrants, lane micro 4x8.
// Epilogue: 32 global_atomic_add_f32 per thread into qh_s / kh4 (8-way
// accumulation across d-slices; ~3.5M atomics total, L2-side).
// ---------------------------------------------------------------------------
__global__ __launch_bounds__(256) void proj_part(
    const float* __restrict__ qin, const float* __restrict__ kin,
    const float* __restrict__ wq,  const float* __restrict__ wk,
    const int* __restrict__ valid_lens,
    float* __restrict__ qh_s, float* __restrict__ khf)
{
    __shared__ float Xs[64][68];     // 17.4 KB
    __shared__ float Ws[64][132];    // 33.8 KB

    const int t = threadIdx.x, bid = blockIdx.x;
    const int ds = bid & 7, tile = bid >> 3;    // tile 0..79
    const int d0 = ds * 64;
    const float* X; const float* W;
    int kb = 0, kr0 = 0;
    bool is_q;
    if (tile < 16) { X = qin + (size_t)tile * 64 * D_; W = wq; is_q = true; }
    else {
        int kt = tile - 16; kb = kt >> 4; kr0 = (kt & 15) * 64;
        if (kr0 >= valid_lens[kb]) return;
        X = kin + ((size_t)kb * K_ + kr0) * D_;
        W = wk;
        is_q = false;
    }
    const int R0 = tile * 64;
    const float SC = 2.0f * LOG2E;   // folded e^{2x} exponent scale

#pragma unroll
    for (int i = 0; i < 4; ++i) {        // stage X: 64 r x 64 d
        int idx = t + i * 256;
        int row = idx >> 4, dq = (idx & 15) * 4;
        float4 xv = *(const float4*)&X[(size_t)row * D_ + d0 + dq];
        Xs[dq+0][row] = xv.x; Xs[dq+1][row] = xv.y;
        Xs[dq+2][row] = xv.z; Xs[dq+3][row] = xv.w;
    }
#pragma unroll
    for (int i = 0; i < 8; ++i) {        // stage W (x SC): 128 h x 64 d
        int idx = t + i * 256;
        int h = idx >> 4, dq = (idx & 15) * 4;
        float4 wv = *(const float4*)&W[(size_t)h * D_ + d0 + dq];
        Ws[dq+0][h] = wv.x * SC; Ws[dq+1][h] = wv.y * SC;
        Ws[dq+2][h] = wv.z * SC; Ws[dq+3][h] = wv.w * SC;
    }
    __syncthreads();

    const int wid = t >> 6, lane = t & 63;
    const int r0 = (wid >> 1) * 32 + (lane >> 3) * 4;
    const int h0 = (wid & 1)  * 64 + (lane & 7)  * 8;
    float c[4][8] = {};

#pragma unroll 4
    for (int kk = 0; kk < 64; ++kk) {
        float xr[4], wr[8];
        *(float4*)&xr[0] = *(const float4*)&Xs[kk][r0];
        *(float4*)&wr[0] = *(const float4*)&Ws[kk][h0];
        *(float4*)&wr[4] = *(const float4*)&Ws[kk][h0 + 4];
#pragma unroll
        for (int i = 0; i < 4; ++i)
#pragma unroll
            for (int j = 0; j < 8; ++j) c[i][j] += xr[i] * wr[j];
    }

    if (is_q) {
#pragma unroll
        for (int i = 0; i < 4; ++i) {
            float* rp = qh_s + (size_t)(R0 + r0 + i) * 128 + h0;
#pragma unroll
            for (int j = 0; j < 8; ++j) atomicAdd(&rp[j], c[i][j]);
        }
    } else {
        // kh4 layout: [(b*32 + h/4) * K + kk] as float4 -> float index *4 + (h&3)
#pragma unroll
        for (int i = 0; i < 4; ++i) {
            int kk = kr0 + r0 + i;
#pragma unroll
            for (int j = 0; j < 8; ++j) {
                int h = h0 + j;
                size_t idx = (((size_t)kb * 32 + (h >> 2)) * K_ + kk) * 4 + (h & 3);
                atomicAdd(&khf[idx], c[i][j]);
            }
        }
    }
}

// ---------------------------------------------------------------------------
// attn_part: STATIC oversubscribed grid, no atomics. 1024 blocks x 256 thr
// (4 waves), item = (b, 8-q tile, 128-k chunk). 28.6 KB LDS -> 5 blocks/CU.
// Mapping: qt = bid&31 (XCD axis), kc = (bid>>5)&7, b = bid>>8.
// Phase B: 2-way h-split (hh = t>>7, 16 hq each), kh prefetch depth 1,
// exp2-tanh (3 VALU + 2 trans / element), 512 elements/thread.
// No softmax max-pass (|score| <= Sum|w_v| ~ 5, exp2 safe).
// Phase D: 2-way k-split over 64 k, v prefetch; o_part has 8 slices.
// ---------------------------------------------------------------------------
__global__ __launch_bounds__(256) void attn_part(
    const float* __restrict__ qh_s, const float4* __restrict__ kh4,
    const float* __restrict__ wvg,  const int* __restrict__ valid_lens,
    const float* __restrict__ vin,
    float* __restrict__ s_part, float4* __restrict__ o_part)
{
    __shared__ float  qv[1024];
    __shared__ float  wvs[128];
    __shared__ float  ptmp[8][128];
    __shared__ float  p[8][128];
    __shared__ float  sred[2][8];
    __shared__ float4 otmp[8][128];

    const int t   = threadIdx.x;
    const int bid = blockIdx.x;
    const int qt  = bid & 31, kc = (bid >> 5) & 7, b = bid >> 8;
    const int q0  = qt * 8;
    const int vl  = valid_lens[b];
    const int kbase = kc * 128;
    if (kbase >= vl) return;
    const int klen = min(128, vl - kbase);

#pragma unroll
    for (int i = 0; i < 4; ++i)
        qv[t + i * 256] = qh_s[(size_t)(b*Q_ + q0) * H_ + t + i * 256];
    if (t < 128) wvs[t] = wvg[t] * (-2.0f * LOG2E);
    __syncthreads();

    const int k  = t & 127;             // k within chunk
    const int hh = t >> 7;              // h-half (waves 0,1 = hh0; 2,3 = hh1)
    const bool active = k < klen;

    // ---- Phase B: scores (2-way h-split, kh prefetch depth 1) ----
    float acc[8] = {};
    if (active) {
        const float4* khp = kh4 + (size_t)b * 32 * K_ + (kbase + k)
                          + (size_t)(hh * 16) * K_;
        float4 kxn = khp[0];
#pragma unroll 4
        for (int i = 0; i < 16; ++i) {
            float4 kx = kxn;
            int ni = (i < 15) ? i + 1 : 15;
            kxn = khp[(size_t)ni * K_];
            const int hq = hh * 16 + i;
            float w4[4], kxa[4];
            *(float4*)&w4[0]  = *(const float4*)&wvs[hq*4];
            *(float4*)&kxa[0] = kx;
#pragma unroll
            for (int qi = 0; qi < 8; ++qi) {
                float q4[4];
                *(float4*)&q4[0] = *(const float4*)&qv[qi*128 + hq*4];
#pragma unroll
                for (int j = 0; j < 4; ++j) {
                    float tt = __builtin_amdgcn_exp2f(q4[j] + kxa[j]);
                    float rr = __builtin_amdgcn_rcpf(tt + 1.0f);
                    acc[qi] = fmaf(w4[j], rr, acc[qi]);
                }
            }
        }
    }
    if (hh == 1) {
#pragma unroll
        for (int qi = 0; qi < 8; ++qi) ptmp[qi][k] = acc[qi];
    }
    __syncthreads();

    if (hh == 0) {
        float psum8[8];
#pragma unroll
        for (int qi = 0; qi < 8; ++qi) {
            float a = acc[qi] + ptmp[qi][k];
            // a is already log2(p) (all scale factors folded upstream)
            float e = active ? __builtin_amdgcn_exp2f(a) : 0.f;
            p[qi][k] = e;
            psum8[qi] = e;
        }
#pragma unroll
        for (int off = 32; off > 0; off >>= 1)
#pragma unroll
            for (int qi = 0; qi < 8; ++qi) psum8[qi] += __shfl_xor(psum8[qi], off);
        if ((t & 63) == 0) {
#pragma unroll
            for (int qi = 0; qi < 8; ++qi) sred[t >> 6][qi] = psum8[qi];
        }
    }
    __syncthreads();                    // p + sred ready

    if (t == 0) {
#pragma unroll
        for (int qi = 0; qi < 8; ++qi)
            s_part[(size_t)(b*Q_ + q0 + qi) * 8 + kc] = sred[0][qi] + sred[1][qi];
    }

    // ---- Phase D: partial PV (2-way k-split over 64, v prefetch) ----
    const int col  = t & 127;           // float4 column of DV/4
    const int half = t >> 7;
    const int kb2  = half * 64;
    const int ke2  = min(klen, kb2 + 64);
    const float4* vb = (const float4*)vin + (size_t)b * K_ * 128
                     + (size_t)kbase * 128;

    float4 o[8];
#pragma unroll
    for (int qi = 0; qi < 8; ++qi) o[qi] = make_float4(0.f, 0.f, 0.f, 0.f);

    int kk = kb2;
    const int nfull = (ke2 > kb2) ? ((ke2 - kb2) >> 2) : 0;
    if (nfull > 0) {
        float4 n0v = vb[(size_t)(kk+0)*128 + col];
        float4 n1v = vb[(size_t)(kk+1)*128 + col];
        float4 n2v = vb[(size_t)(kk+2)*128 + col];
        float4 n3v = vb[(size_t)(kk+3)*128 + col];
        for (int g = 0; g < nfull; ++g) {
            float4 v0 = n0v, v1 = n1v, v2 = n2v, v3 = n3v;
            int kn = kk + 4;
            if (g + 1 < nfull) {
                n0v = vb[(size_t)(kn+0)*128 + col];
                n1v = vb[(size_t)(kn+1)*128 + col];
                n2v = vb[(size_t)(kn+2)*128 + col];
                n3v = vb[(size_t)(kn+3)*128 + col];
            }
#pragma unroll
            for (int qi = 0; qi < 8; ++qi) {
                float4 pq = *(const float4*)&p[qi][kk];
                o[qi].x += pq.x*v0.x + pq.y*v1.x + pq.z*v2.x + pq.w*v3.x;
                o[qi].y += pq.x*v0.y + pq.y*v1.y + pq.z*v2.y + pq.w*v3.y;
                o[qi].z += pq.x*v0.z + pq.y*v1.z + pq.z*v2.z + pq.w*v3.z;
                o[qi].w += pq.x*v0.w + pq.y*v1.w + pq.z*v2.w + pq.w*v3.w;
            }
            kk = kn;
        }
    }
    for (; kk < ke2; ++kk) {
        float4 v0 = vb[(size_t)kk*128 + col];
#pragma unroll
        for (int qi = 0; qi < 8; ++qi) {
            float pk = p[qi][kk];
            o[qi].x += pk*v0.x; o[qi].y += pk*v0.y;
            o[qi].z += pk*v0.z; o[qi].w += pk*v0.w;
        }
    }

    if (half == 1) {
#pragma unroll
        for (int qi = 0; qi < 8; ++qi) otmp[qi][col] = o[qi];
    }
    __syncthreads();
    if (half == 0) {
#pragma unroll
        for (int qi = 0; qi < 8; ++qi) {
            float4 r = otmp[qi][col];
            o[qi].x += r.x; o[qi].y += r.y; o[qi].z += r.z; o[qi].w += r.w;
            o_part[((size_t)kc * 1024 + (b*Q_ + q0 + qi)) * 128 + col] = o[qi];
        }
    }
}

// ---------------------------------------------------------------------------
// finalize: out[row][col] = (Sum_{ch<nch} o_part[ch][row][col]) * rcp(Sum s).
// nch = ceil(vl/128) <= 8.
// ---------------------------------------------------------------------------
__global__ __launch_bounds__(256) void finalize_kernel(
    const float4* __restrict__ o_part, const float* __restrict__ s_part,
    const int* __restrict__ valid_lens, float4* __restrict__ out)
{
    int gid = blockIdx.x * 256 + threadIdx.x;     // [0, 131072)
    int row = gid >> 7, col = gid & 127;
    int b = row >> 8;
    int nch = (valid_lens[b] + 127) >> 7;
    float ssum = 0.f;
    float4 o = make_float4(0.f, 0.f, 0.f, 0.f);
    for (int ch = 0; ch < nch; ++ch) {
        ssum += s_part[(size_t)row * 8 + ch];
        float4 r = o_part[((size_t)ch * 1024 + row) * 128 + col];
        o.x += r.x; o.y += r.y; o.z += r.z; o.w += r.w;
    }
    float rs = __builtin_amdgcn_rcpf(ssum);
    out[gid] = make_float4(o.x*rs, o.y*rs, o.z*rs, o.w*rs);
}

extern "C" void kernel_launch(void* const* d_in, const int* in_sizes, int n_in,
                              void* d_out, int out_size, void* d_ws, size_t ws_size,
                              hipStream_t stream)
{
    const float* q  = (const float*)d_in[0];
    const float* k  = (const float*)d_in[1];
    const float* v  = (const float*)d_in[2];
    const int*   vl = (const int*)d_in[3];
    const float* wq = (const float*)d_in[4];
    const float* wk = (const float*)d_in[5];
    const float* wv = (const float*)d_in[6];
    float* out = (float*)d_out;

    float* qh_s  = (float*)d_ws;                      //  131072 f
    float* kh4   = qh_s  + (size_t)B_*Q_*H_;          //  524288 f
    float* s_prt = kh4   + (size_t)B_*H_*K_;          //    8192 f
    float* o_prt = s_prt + (size_t)B_*Q_*8;           // 4194304 f (16 MB)

    // zero the atomic accumulators (2.6 MB, L2-resident, graph-safe)
    hipMemsetAsync(qh_s, 0, (size_t)(B_*Q_*H_ + B_*H_*K_) * sizeof(float), stream);

    proj_part      <<<dim3(640),  dim3(256), 0, stream>>>(q, k, wq, wk, vl, qh_s, kh4);
    attn_part      <<<dim3(1024), dim3(256), 0, stream>>>(qh_s, (const float4*)kh4, wv, vl, v, s_prt, (float4*)o_prt);
    finalize_kernel<<<dim3(512),  dim3(256), 0, stream>>>((const float4*)o_prt, s_prt, vl, (float4*)out);
}

// Round 3
// 160.905 us; speedup vs baseline: 1.8371x; 1.8371x over previous
//
#include <hip/hip_runtime.h>

// AdditiveAttention: B=4, Q=256, K=1024, DQ=DK=DV=512, H=128
#define B_ 4
#define Q_ 256
#define K_ 1024
#define D_ 512
#define H_ 128
#define DV_ 512
#define LOG2E 1.4426950408889634f

// tanh via exp2: tanh(x) = 1 - 2/(1+e^{2x}).  The constant term SUM_h w_h
// cancels in softmax, so  p = exp2( SUM_h (-2*log2e*w_h) * rcp(1 + exp2(sc)) )
// with sc = 2*log2e*(qh+kh).  2*log2e is folded into the staged W values in
// proj_part; -2*log2e into w_v at attn staging.  3 VALU + 2 trans / element.
//
// Round-3 proj: full-D reduction IN-BLOCK (8 LDS chunks of 64 d), killing
// both the 42 MB psum round-trip (round 1) and the serialized global
// atomics (round 2: 173 us, VALUBusy 1.4%).  32-row x 128-h tiles, grid 160,
// XOR-swizzled transposed LDS staging (write-conflict-free), T14 overlap
// (next chunk's global loads issued before compute, ds_write after barrier).

// ---------------------------------------------------------------------------
// proj_part: tile = 32 rows x 128 h, full D in-block. Grid 160 =
// [q tiles 0..31][k tiles 32..159]. 4 waves = h-quadrants (32 h each);
// lane micro 4r x 4h. ~40 KB LDS. Epilogue: direct float4 stores to
// qh_s / kh4 (no cross-block reduction exists).
// ---------------------------------------------------------------------------
__global__ __launch_bounds__(256) void proj_part(
    const float* __restrict__ qin, const float* __restrict__ kin,
    const float* __restrict__ wq,  const float* __restrict__ wk,
    const int* __restrict__ valid_lens,
    float* __restrict__ qh_s, float* __restrict__ khf)
{
    __shared__ float Xs[64 * 32];    //  8 KB, [d][row],  col ^= ((d>>2)&7)<<2
    __shared__ float Ws[64 * 128];   // 32 KB, [d][h],    col ^= ((d>>2)&7)<<2

    const int t = threadIdx.x, tile = blockIdx.x;
    const float* X; const float* W;
    int kb = 0, kr0 = 0;
    bool is_q;
    if (tile < 32) { X = qin + (size_t)tile * 32 * D_; W = wq; is_q = true; }
    else {
        int kt = tile - 32; kb = kt >> 5; kr0 = (kt & 31) * 32;
        if (kr0 >= valid_lens[kb]) return;
        X = kin + ((size_t)kb * K_ + kr0) * D_;
        W = wk;
        is_q = false;
    }
    const float SC = 2.0f * LOG2E;   // folded e^{2x} exponent scale

    // staging decode (same for every chunk)
    const int xrow = (t + 0) >> 4,        xdq = (t & 15) * 4;        // i=0
    const int xrow1 = (t + 256) >> 4;                                // i=1
    // W: idx = t + i*256: h = idx>>4, dq = (idx&15)*4
    float4 xr0, xr1, wr8[8];

    #define LOADX(c) do { \
        xr0 = *(const float4*)&X[(size_t)xrow  * D_ + (c)*64 + xdq]; \
        xr1 = *(const float4*)&X[(size_t)xrow1 * D_ + (c)*64 + xdq]; } while (0)
    #define LOADW(c) do { \
        _Pragma("unroll") \
        for (int i = 0; i < 8; ++i) { \
            int idx = t + i * 256; \
            wr8[i] = *(const float4*)&W[(size_t)(idx >> 4) * D_ + (c)*64 + (idx & 15) * 4]; } } while (0)
    #define WRITE_LDS() do { \
        { float v[4]; *(float4*)v = xr0; \
          _Pragma("unroll") \
          for (int j = 0; j < 4; ++j) { int d = xdq + j; \
              Xs[d * 32 + (xrow ^ (((d >> 2) & 7) << 2))] = v[j]; } } \
        { float v[4]; *(float4*)v = xr1; \
          _Pragma("unroll") \
          for (int j = 0; j < 4; ++j) { int d = xdq + j; \
              Xs[d * 32 + (xrow1 ^ (((d >> 2) & 7) << 2))] = v[j]; } } \
        _Pragma("unroll") \
        for (int i = 0; i < 8; ++i) { \
            int idx = t + i * 256; int h = idx >> 4, dq = (idx & 15) * 4; \
            float v[4]; *(float4*)v = wr8[i]; \
            _Pragma("unroll") \
            for (int j = 0; j < 4; ++j) { int d = dq + j; \
                Ws[d * 128 + (h ^ (((d >> 2) & 7) << 2))] = v[j]; } } } while (0)

    const int wid = t >> 6, lane = t & 63;
    const int r0 = (lane & 7) * 4;                    // 4 rows
    const int h0 = wid * 32 + (lane >> 3) * 4;        // 4 h
    float c[4][4] = {};

    LOADX(0); LOADW(0);
    WRITE_LDS();

    for (int ch = 0; ch < 8; ++ch) {
        __syncthreads();                  // LDS chunk ready
        if (ch < 7) { LOADX(ch + 1); LOADW(ch + 1); }   // overlap with compute
#pragma unroll 8
        for (int kk = 0; kk < 64; ++kk) {
            const int xc = ((kk >> 2) & 7) << 2;
            float xr[4], wr[4];
            *(float4*)&xr[0] = *(const float4*)&Xs[kk * 32  + (r0 ^ xc)];
            *(float4*)&wr[0] = *(const float4*)&Ws[kk * 128 + (h0 ^ xc)];
#pragma unroll
            for (int i = 0; i < 4; ++i)
#pragma unroll
                for (int j = 0; j < 4; ++j) c[i][j] = fmaf(xr[i], wr[j], c[i][j]);
        }
        __syncthreads();                  // all reads done
        if (ch < 7) WRITE_LDS();          // stage next chunk
    }

    // fold SC here (cheaper than scaling W: 16 mults vs 32 per thread)
#pragma unroll
    for (int i = 0; i < 4; ++i)
#pragma unroll
        for (int j = 0; j < 4; ++j) c[i][j] *= SC;

    if (is_q) {
        const int R0 = tile * 32;
#pragma unroll
        for (int i = 0; i < 4; ++i)
            *(float4*)&qh_s[(size_t)(R0 + r0 + i) * 128 + h0] = *(const float4*)&c[i][0];
    } else {
        // kh4 layout: float4[(b*32 + h/4) * K + kk]
        const int h2 = h0 >> 2;
#pragma unroll
        for (int i = 0; i < 4; ++i) {
            size_t idx = ((size_t)kb * 32 + h2) * K_ + (kr0 + r0 + i);
            *(float4*)&khf[idx * 4] = *(const float4*)&c[i][0];
        }
    }
    #undef LOADX
    #undef LOADW
    #undef WRITE_LDS
}

// ---------------------------------------------------------------------------
// attn_part: STATIC oversubscribed grid, no atomics. 1024 blocks x 256 thr
// (4 waves), item = (b, 8-q tile, 128-k chunk). 28.6 KB LDS -> 5 blocks/CU.
// Mapping: qt = bid&31 (XCD axis), kc = (bid>>5)&7, b = bid>>8.
// Phase B: 2-way h-split (hh = t>>7, 16 hq each), kh prefetch depth 1,
// exp2-tanh (3 VALU + 2 trans / element), 512 elements/thread.
// No softmax max-pass (|score| <= Sum|w_v| ~ 5, exp2 safe).
// Phase D: 2-way k-split over 64 k, v prefetch; o_part has 8 slices.
// ---------------------------------------------------------------------------
__global__ __launch_bounds__(256) void attn_part(
    const float* __restrict__ qh_s, const float4* __restrict__ kh4,
    const float* __restrict__ wvg,  const int* __restrict__ valid_lens,
    const float* __restrict__ vin,
    float* __restrict__ s_part, float4* __restrict__ o_part)
{
    __shared__ float  qv[1024];
    __shared__ float  wvs[128];
    __shared__ float  ptmp[8][128];
    __shared__ float  p[8][128];
    __shared__ float  sred[2][8];
    __shared__ float4 otmp[8][128];

    const int t   = threadIdx.x;
    const int bid = blockIdx.x;
    const int qt  = bid & 31, kc = (bid >> 5) & 7, b = bid >> 8;
    const int q0  = qt * 8;
    const int vl  = valid_lens[b];
    const int kbase = kc * 128;
    if (kbase >= vl) return;
    const int klen = min(128, vl - kbase);

#pragma unroll
    for (int i = 0; i < 4; ++i)
        qv[t + i * 256] = qh_s[(size_t)(b*Q_ + q0) * H_ + t + i * 256];
    if (t < 128) wvs[t] = wvg[t] * (-2.0f * LOG2E);
    __syncthreads();

    const int k  = t & 127;             // k within chunk
    const int hh = t >> 7;              // h-half (waves 0,1 = hh0; 2,3 = hh1)
    const bool active = k < klen;

    // ---- Phase B: scores (2-way h-split, kh prefetch depth 1) ----
    float acc[8] = {};
    if (active) {
        const float4* khp = kh4 + (size_t)b * 32 * K_ + (kbase + k)
                          + (size_t)(hh * 16) * K_;
        float4 kxn = khp[0];
#pragma unroll 4
        for (int i = 0; i < 16; ++i) {
            float4 kx = kxn;
            int ni = (i < 15) ? i + 1 : 15;
            kxn = khp[(size_t)ni * K_];
            const int hq = hh * 16 + i;
            float w4[4], kxa[4];
            *(float4*)&w4[0]  = *(const float4*)&wvs[hq*4];
            *(float4*)&kxa[0] = kx;
#pragma unroll
            for (int qi = 0; qi < 8; ++qi) {
                float q4[4];
                *(float4*)&q4[0] = *(const float4*)&qv[qi*128 + hq*4];
#pragma unroll
                for (int j = 0; j < 4; ++j) {
                    float tt = __builtin_amdgcn_exp2f(q4[j] + kxa[j]);
                    float rr = __builtin_amdgcn_rcpf(tt + 1.0f);
                    acc[qi] = fmaf(w4[j], rr, acc[qi]);
                }
            }
        }
    }
    if (hh == 1) {
#pragma unroll
        for (int qi = 0; qi < 8; ++qi) ptmp[qi][k] = acc[qi];
    }
    __syncthreads();

    if (hh == 0) {
        float psum8[8];
#pragma unroll
        for (int qi = 0; qi < 8; ++qi) {
            float a = acc[qi] + ptmp[qi][k];
            // a is already log2(p) (all scale factors folded upstream)
            float e = active ? __builtin_amdgcn_exp2f(a) : 0.f;
            p[qi][k] = e;
            psum8[qi] = e;
        }
#pragma unroll
        for (int off = 32; off > 0; off >>= 1)
#pragma unroll
            for (int qi = 0; qi < 8; ++qi) psum8[qi] += __shfl_xor(psum8[qi], off);
        if ((t & 63) == 0) {
#pragma unroll
            for (int qi = 0; qi < 8; ++qi) sred[t >> 6][qi] = psum8[qi];
        }
    }
    __syncthreads();                    // p + sred ready

    if (t == 0) {
#pragma unroll
        for (int qi = 0; qi < 8; ++qi)
            s_part[(size_t)(b*Q_ + q0 + qi) * 8 + kc] = sred[0][qi] + sred[1][qi];
    }

    // ---- Phase D: partial PV (2-way k-split over 64, v prefetch) ----
    const int col  = t & 127;           // float4 column of DV/4
    const int half = t >> 7;
    const int kb2  = half * 64;
    const int ke2  = min(klen, kb2 + 64);
    const float4* vb = (const float4*)vin + (size_t)b * K_ * 128
                     + (size_t)kbase * 128;

    float4 o[8];
#pragma unroll
    for (int qi = 0; qi < 8; ++qi) o[qi] = make_float4(0.f, 0.f, 0.f, 0.f);

    int kk = kb2;
    const int nfull = (ke2 > kb2) ? ((ke2 - kb2) >> 2) : 0;
    if (nfull > 0) {
        float4 n0v = vb[(size_t)(kk+0)*128 + col];
        float4 n1v = vb[(size_t)(kk+1)*128 + col];
        float4 n2v = vb[(size_t)(kk+2)*128 + col];
        float4 n3v = vb[(size_t)(kk+3)*128 + col];
        for (int g = 0; g < nfull; ++g) {
            float4 v0 = n0v, v1 = n1v, v2 = n2v, v3 = n3v;
            int kn = kk + 4;
            if (g + 1 < nfull) {
                n0v = vb[(size_t)(kn+0)*128 + col];
                n1v = vb[(size_t)(kn+1)*128 + col];
                n2v = vb[(size_t)(kn+2)*128 + col];
                n3v = vb[(size_t)(kn+3)*128 + col];
            }
#pragma unroll
            for (int qi = 0; qi < 8; ++qi) {
                float4 pq = *(const float4*)&p[qi][kk];
                o[qi].x += pq.x*v0.x + pq.y*v1.x + pq.z*v2.x + pq.w*v3.x;
                o[qi].y += pq.x*v0.y + pq.y*v1.y + pq.z*v2.y + pq.w*v3.y;
                o[qi].z += pq.x*v0.z + pq.y*v1.z + pq.z*v2.z + pq.w*v3.z;
                o[qi].w += pq.x*v0.w + pq.y*v1.w + pq.z*v2.w + pq.w*v3.w;
            }
            kk = kn;
        }
    }
    for (; kk < ke2; ++kk) {
        float4 v0 = vb[(size_t)kk*128 + col];
#pragma unroll
        for (int qi = 0; qi < 8; ++qi) {
            float pk = p[qi][kk];
            o[qi].x += pk*v0.x; o[qi].y += pk*v0.y;
            o[qi].z += pk*v0.z; o[qi].w += pk*v0.w;
        }
    }

    if (half == 1) {
#pragma unroll
        for (int qi = 0; qi < 8; ++qi) otmp[qi][col] = o[qi];
    }
    __syncthreads();
    if (half == 0) {
#pragma unroll
        for (int qi = 0; qi < 8; ++qi) {
            float4 r = otmp[qi][col];
            o[qi].x += r.x; o[qi].y += r.y; o[qi].z += r.z; o[qi].w += r.w;
            o_part[((size_t)kc * 1024 + (b*Q_ + q0 + qi)) * 128 + col] = o[qi];
        }
    }
}

// ---------------------------------------------------------------------------
// finalize: out[row][col] = (Sum_{ch<nch} o_part[ch][row][col]) * rcp(Sum s).
// nch = ceil(vl/128) <= 8.
// ---------------------------------------------------------------------------
__global__ __launch_bounds__(256) void finalize_kernel(
    const float4* __restrict__ o_part, const float* __restrict__ s_part,
    const int* __restrict__ valid_lens, float4* __restrict__ out)
{
    int gid = blockIdx.x * 256 + threadIdx.x;     // [0, 131072)
    int row = gid >> 7, col = gid & 127;
    int b = row >> 8;
    int nch = (valid_lens[b] + 127) >> 7;
    float ssum = 0.f;
    float4 o = make_float4(0.f, 0.f, 0.f, 0.f);
    for (int ch = 0; ch < nch; ++ch) {
        ssum += s_part[(size_t)row * 8 + ch];
        float4 r = o_part[((size_t)ch * 1024 + row) * 128 + col];
        o.x += r.x; o.y += r.y; o.z += r.z; o.w += r.w;
    }
    float rs = __builtin_amdgcn_rcpf(ssum);
    out[gid] = make_float4(o.x*rs, o.y*rs, o.z*rs, o.w*rs);
}

extern "C" void kernel_launch(void* const* d_in, const int* in_sizes, int n_in,
                              void* d_out, int out_size, void* d_ws, size_t ws_size,
                              hipStream_t stream)
{
    const float* q  = (const float*)d_in[0];
    const float* k  = (const float*)d_in[1];
    const float* v  = (const float*)d_in[2];
    const int*   vl = (const int*)d_in[3];
    const float* wq = (const float*)d_in[4];
    const float* wk = (const float*)d_in[5];
    const float* wv = (const float*)d_in[6];
    float* out = (float*)d_out;

    float* qh_s  = (float*)d_ws;                      //  131072 f
    float* kh4   = qh_s  + (size_t)B_*Q_*H_;          //  524288 f
    float* s_prt = kh4   + (size_t)B_*H_*K_;          //    8192 f
    float* o_prt = s_prt + (size_t)B_*Q_*8;           // 4194304 f (16 MB)

    proj_part      <<<dim3(160),  dim3(256), 0, stream>>>(q, k, wq, wk, vl, qh_s, kh4);
    attn_part      <<<dim3(1024), dim3(256), 0, stream>>>(qh_s, (const float4*)kh4, wv, vl, v, s_prt, (float4*)o_prt);
    finalize_kernel<<<dim3(512),  dim3(256), 0, stream>>>((const float4*)o_prt, s_prt, vl, (float4*)out);
}

// Round 4
// 115.300 us; speedup vs baseline: 2.5637x; 1.3955x over previous
//
#include <hip/hip_runtime.h>

// AdditiveAttention: B=4, Q=256, K=1024, DQ=DK=DV=512, H=128
#define B_ 4
#define Q_ 256
#define K_ 1024
#define D_ 512
#define H_ 128
#define DV_ 512
#define LOG2E 1.4426950408889634f

// tanh via exp2: tanh(x) = 1 - 2/(1+e^{2x}).  SUM_h w_h cancels in softmax:
// p = exp2( SUM_h (-2*log2e*w_h) * rcp(1 + exp2(2*log2e*(qh+kh))) ).
// 2*log2e folded at proj_reduce; -2*log2e into w_v at attn staging.
//
// Round-4: LESSON from r2/r3 counters — these kernels are latency/parallelism
// bound (r3: attn 50us @ occupancy 9.5%, VALUBusy 20%, HBM 4.5% after halving
// blocks), NOT traffic-bound.  Structure reverts to round-1's block counts
// (640/640/2048); the only traffic trim kept is proj doing 128d in-block
// (psum 21->10.5 MB, 4 slices) which preserves grid 640.

// ---------------------------------------------------------------------------
// proj_part: tile = 32 rows x 128 h x 128 d (2 LDS chunks of 64 d).
// Grid 640 = [ds:4 == bid&3][tile:160 = 32 q + 128 k].  4 waves = h-quadrants,
// lane micro 4r x 4h.  40 KB LDS, XOR-swizzled transposed staging
// (write-conflict-free), next-chunk global loads overlap compute (T14).
// Epilogue: float4 partials -> psum[ds] (no atomics, no cross-block reduce).
// ---------------------------------------------------------------------------
__global__ __launch_bounds__(256) void proj_part(
    const float* __restrict__ qin, const float* __restrict__ kin,
    const float* __restrict__ wq,  const float* __restrict__ wk,
    const int* __restrict__ valid_lens, float* __restrict__ psum)
{
    __shared__ float Xs[64 * 32];    //  8 KB, [d][row],  col ^= ((d>>2)&7)<<2
    __shared__ float Ws[64 * 128];   // 32 KB, [d][h],    col ^= ((d>>2)&7)<<2

    const int t = threadIdx.x, bid = blockIdx.x;
    const int ds = bid & 3, tile = bid >> 2;     // tile 0..159
    const float* X; const float* W;
    int R0;
    if (tile < 32) { X = qin + (size_t)tile * 32 * D_; W = wq; R0 = tile * 32; }
    else {
        int kt = tile - 32, kb = kt >> 5, kr0 = (kt & 31) * 32;
        if (kr0 >= valid_lens[kb]) return;
        X = kin + ((size_t)kb * K_ + kr0) * D_;
        W = wk;
        R0 = 1024 + kt * 32;
    }

    const int xrow  = (t + 0) >> 4, xdq = (t & 15) * 4;
    const int xrow1 = (t + 256) >> 4;
    float4 xr0, xr1, wr8[8];

    #define LOADX(c) do { \
        xr0 = *(const float4*)&X[(size_t)xrow  * D_ + (c)*64 + xdq]; \
        xr1 = *(const float4*)&X[(size_t)xrow1 * D_ + (c)*64 + xdq]; } while (0)
    #define LOADW(c) do { \
        _Pragma("unroll") \
        for (int i = 0; i < 8; ++i) { \
            int idx = t + i * 256; \
            wr8[i] = *(const float4*)&W[(size_t)(idx >> 4) * D_ + (c)*64 + (idx & 15) * 4]; } } while (0)
    #define WRITE_LDS() do { \
        { float v[4]; *(float4*)v = xr0; \
          _Pragma("unroll") \
          for (int j = 0; j < 4; ++j) { int d = xdq + j; \
              Xs[d * 32 + (xrow ^ (((d >> 2) & 7) << 2))] = v[j]; } } \
        { float v[4]; *(float4*)v = xr1; \
          _Pragma("unroll") \
          for (int j = 0; j < 4; ++j) { int d = xdq + j; \
              Xs[d * 32 + (xrow1 ^ (((d >> 2) & 7) << 2))] = v[j]; } } \
        _Pragma("unroll") \
        for (int i = 0; i < 8; ++i) { \
            int idx = t + i * 256; int h = idx >> 4, dq = (idx & 15) * 4; \
            float v[4]; *(float4*)v = wr8[i]; \
            _Pragma("unroll") \
            for (int j = 0; j < 4; ++j) { int d = dq + j; \
                Ws[d * 128 + (h ^ (((d >> 2) & 7) << 2))] = v[j]; } } } while (0)

    const int wid = t >> 6, lane = t & 63;
    const int r0 = (lane & 7) * 4;                    // 4 rows
    const int h0 = wid * 32 + (lane >> 3) * 4;        // 4 h
    float c[4][4] = {};

    const int c0 = ds * 2;                            // 2 chunks: c0, c0+1
    LOADX(c0); LOADW(c0);
    WRITE_LDS();

    for (int cc = 0; cc < 2; ++cc) {
        __syncthreads();                  // LDS chunk ready
        if (cc < 1) { LOADX(c0 + 1); LOADW(c0 + 1); }
#pragma unroll 8
        for (int kk = 0; kk < 64; ++kk) {
            const int xc = ((kk >> 2) & 7) << 2;
            float xr[4], wr[4];
            *(float4*)&xr[0] = *(const float4*)&Xs[kk * 32  + (r0 ^ xc)];
            *(float4*)&wr[0] = *(const float4*)&Ws[kk * 128 + (h0 ^ xc)];
#pragma unroll
            for (int i = 0; i < 4; ++i)
#pragma unroll
                for (int j = 0; j < 4; ++j) c[i][j] = fmaf(xr[i], wr[j], c[i][j]);
        }
        __syncthreads();                  // all reads done
        if (cc < 1) WRITE_LDS();
    }

    float* outp = psum + ((size_t)ds * 5120 + R0) * 128;
#pragma unroll
    for (int i = 0; i < 4; ++i)
        *(float4*)&outp[(size_t)(r0 + i) * 128 + h0] = *(const float4*)&c[i][0];

    #undef LOADX
    #undef LOADW
    #undef WRITE_LDS
}

// ---------------------------------------------------------------------------
// proj_reduce: sum 4 d-slices, scale by 2*log2e, write qh_s / kh4 layouts.
// Masked k rows skip.  Grid 640.
// ---------------------------------------------------------------------------
__global__ __launch_bounds__(256) void proj_reduce(
    const float* __restrict__ psum, const int* __restrict__ valid_lens,
    float* __restrict__ qh_s, float4* __restrict__ kh4)
{
    int gid = blockIdx.x * 256 + threadIdx.x;    // [0, 163840)
    int row = gid >> 5, c4 = gid & 31;
    int b = 0, kk = 0;
    if (row >= 1024) {
        int r = row - 1024;
        b = r >> 10; kk = r & 1023;
        if (kk >= valid_lens[b]) return;
    }
    float4 s = make_float4(0.f, 0.f, 0.f, 0.f);
#pragma unroll
    for (int ds = 0; ds < 4; ++ds) {
        float4 v = *(const float4*)&psum[((size_t)ds * 5120 + row) * 128 + c4 * 4];
        s.x += v.x; s.y += v.y; s.z += v.z; s.w += v.w;
    }
    const float SC = 2.0f * LOG2E;
    s.x *= SC; s.y *= SC; s.z *= SC; s.w *= SC;
    if (row < 1024) *(float4*)&qh_s[(size_t)row * 128 + c4 * 4] = s;
    else            kh4[((size_t)(b * 32 + c4)) * K_ + kk] = s;
}

// ---------------------------------------------------------------------------
// attn_part: round-1 structure (the latency-tolerant one): 2048 blocks x 256
// thr (4 waves), item = (b, 8-q tile, 64-k chunk); ~1024 active blocks ->
// ~16 waves/CU.  31.3 KB LDS -> 5 blocks/CU.
// Phase B: 4-way h-split (hh = wave, 8 hq each), kh prefetch depth 1,
// exp2-tanh (3 VALU + 2 trans / element), 256 elements/thread.
// Combine: ALL 4 waves participate (2 q-rows each) — was wave-0-serial.
// Phase D: 2-way k-split over 32 k, v prefetch; o_part 16 slices.
// ---------------------------------------------------------------------------
__global__ __launch_bounds__(256) void attn_part(
    const float* __restrict__ qh_s, const float4* __restrict__ kh4,
    const float* __restrict__ wvg,  const int* __restrict__ valid_lens,
    const float* __restrict__ vin,
    float* __restrict__ s_part, float4* __restrict__ o_part)
{
    __shared__ float  qv[1024];
    __shared__ float  wvs[128];
    __shared__ float  ptmp[4][8][64];
    __shared__ float  p[8][64];
    __shared__ float  sred[8];
    __shared__ float4 otmp[8][128];

    const int t   = threadIdx.x;
    const int bid = blockIdx.x;
    const int qt  = bid & 31, kc = (bid >> 5) & 15, b = bid >> 9;
    const int q0  = qt * 8;
    const int vl  = valid_lens[b];
    const int kbase = kc * 64;
    if (kbase >= vl) return;
    const int klen = min(64, vl - kbase);

#pragma unroll
    for (int i = 0; i < 4; ++i)
        qv[t + i * 256] = qh_s[(size_t)(b*Q_ + q0) * H_ + t + i * 256];
    if (t < 128) wvs[t] = wvg[t] * (-2.0f * LOG2E);
    __syncthreads();

    const int k  = t & 63;              // k within chunk
    const int hh = t >> 6;              // h-quarter (== wave id)
    const bool active = k < klen;

    // ---- Phase B: scores (4-way h-split, kh prefetch depth 1) ----
    float acc[8] = {};
    if (active) {
        const float4* khp = kh4 + (size_t)b * 32 * K_ + (kbase + k)
                          + (size_t)(hh * 8) * K_;
        const int hq0 = hh * 8;
        float4 kxn = khp[0];
#pragma unroll
        for (int i = 0; i < 8; ++i) {
            float4 kx = kxn;
            int ni = (i < 7) ? i + 1 : 7;
            kxn = khp[(size_t)ni * K_];
            const int hq = hq0 + i;
            float w4[4], kxa[4];
            *(float4*)&w4[0]  = *(const float4*)&wvs[hq*4];
            *(float4*)&kxa[0] = kx;
#pragma unroll
            for (int qi = 0; qi < 8; ++qi) {
                float q4[4];
                *(float4*)&q4[0] = *(const float4*)&qv[qi*128 + hq*4];
#pragma unroll
                for (int j = 0; j < 4; ++j) {
                    float tt = __builtin_amdgcn_exp2f(q4[j] + kxa[j]);
                    float rr = __builtin_amdgcn_rcpf(tt + 1.0f);
                    acc[qi] = fmaf(w4[j], rr, acc[qi]);
                }
            }
        }
    }
#pragma unroll
    for (int qi = 0; qi < 8; ++qi) ptmp[hh][qi][k] = acc[qi];
    __syncthreads();

    // ---- combine: each wave finishes 2 q-rows (was wave-0-serial x8) ----
    {
        const int qia = hh * 2;
#pragma unroll
        for (int q2 = 0; q2 < 2; ++q2) {
            const int qi = qia + q2;
            float a = ptmp[0][qi][k] + ptmp[1][qi][k]
                    + ptmp[2][qi][k] + ptmp[3][qi][k];
            // a is already log2(p) (all scale factors folded upstream)
            float e = active ? __builtin_amdgcn_exp2f(a) : 0.f;
            p[qi][k] = e;
            float s = e;
#pragma unroll
            for (int off = 32; off > 0; off >>= 1) s += __shfl_xor(s, off);
            if (k == 0) sred[qi] = s;
        }
    }
    __syncthreads();                    // p + sred ready

    if (t < 8)
        s_part[(size_t)(b*Q_ + q0 + t) * 16 + kc] = sred[t];

    // ---- Phase D: partial PV (2-way k-split, v prefetch one 4-group) ----
    const int col  = t & 127;           // float4 column of DV/4
    const int half = t >> 7;
    const int kb2  = half * 32;
    const int ke2  = min(klen, kb2 + 32);
    const float4* vb = (const float4*)vin + (size_t)b * K_ * 128
                     + (size_t)kbase * 128;

    float4 o[8];
#pragma unroll
    for (int qi = 0; qi < 8; ++qi) o[qi] = make_float4(0.f, 0.f, 0.f, 0.f);

    int kk = kb2;
    const int nfull = (ke2 > kb2) ? ((ke2 - kb2) >> 2) : 0;
    if (nfull > 0) {
        float4 n0v = vb[(size_t)(kk+0)*128 + col];
        float4 n1v = vb[(size_t)(kk+1)*128 + col];
        float4 n2v = vb[(size_t)(kk+2)*128 + col];
        float4 n3v = vb[(size_t)(kk+3)*128 + col];
        for (int g = 0; g < nfull; ++g) {
            float4 v0 = n0v, v1 = n1v, v2 = n2v, v3 = n3v;
            int kn = kk + 4;
            if (g + 1 < nfull) {
                n0v = vb[(size_t)(kn+0)*128 + col];
                n1v = vb[(size_t)(kn+1)*128 + col];
                n2v = vb[(size_t)(kn+2)*128 + col];
                n3v = vb[(size_t)(kn+3)*128 + col];
            }
#pragma unroll
            for (int qi = 0; qi < 8; ++qi) {
                float4 pq = *(const float4*)&p[qi][kk];
                o[qi].x += pq.x*v0.x + pq.y*v1.x + pq.z*v2.x + pq.w*v3.x;
                o[qi].y += pq.x*v0.y + pq.y*v1.y + pq.z*v2.y + pq.w*v3.y;
                o[qi].z += pq.x*v0.z + pq.y*v1.z + pq.z*v2.z + pq.w*v3.z;
                o[qi].w += pq.x*v0.w + pq.y*v1.w + pq.z*v2.w + pq.w*v3.w;
            }
            kk = kn;
        }
    }
    for (; kk < ke2; ++kk) {
        float4 v0 = vb[(size_t)kk*128 + col];
#pragma unroll
        for (int qi = 0; qi < 8; ++qi) {
            float pk = p[qi][kk];
            o[qi].x += pk*v0.x; o[qi].y += pk*v0.y;
            o[qi].z += pk*v0.z; o[qi].w += pk*v0.w;
        }
    }

    if (half == 1) {
#pragma unroll
        for (int qi = 0; qi < 8; ++qi) otmp[qi][col] = o[qi];
    }
    __syncthreads();
    if (half == 0) {
#pragma unroll
        for (int qi = 0; qi < 8; ++qi) {
            float4 r = otmp[qi][col];
            o[qi].x += r.x; o[qi].y += r.y; o[qi].z += r.z; o[qi].w += r.w;
            o_part[((size_t)kc * 1024 + (b*Q_ + q0 + qi)) * 128 + col] = o[qi];
        }
    }
}

// ---------------------------------------------------------------------------
// finalize: out[row][col] = (Sum_{ch<nch} o_part[ch][row][col]) * rcp(Sum s).
// nch = ceil(vl/64) <= 16.
// ---------------------------------------------------------------------------
__global__ __launch_bounds__(256) void finalize_kernel(
    const float4* __restrict__ o_part, const float* __restrict__ s_part,
    const int* __restrict__ valid_lens, float4* __restrict__ out)
{
    int gid = blockIdx.x * 256 + threadIdx.x;     // [0, 131072)
    int row = gid >> 7, col = gid & 127;
    int b = row >> 8;
    int nch = (valid_lens[b] + 63) >> 6;
    float ssum = 0.f;
    float4 o = make_float4(0.f, 0.f, 0.f, 0.f);
    for (int ch = 0; ch < nch; ++ch) {
        ssum += s_part[(size_t)row * 16 + ch];
        float4 r = o_part[((size_t)ch * 1024 + row) * 128 + col];
        o.x += r.x; o.y += r.y; o.z += r.z; o.w += r.w;
    }
    float rs = __builtin_amdgcn_rcpf(ssum);
    out[gid] = make_float4(o.x*rs, o.y*rs, o.z*rs, o.w*rs);
}

extern "C" void kernel_launch(void* const* d_in, const int* in_sizes, int n_in,
                              void* d_out, int out_size, void* d_ws, size_t ws_size,
                              hipStream_t stream)
{
    const float* q  = (const float*)d_in[0];
    const float* k  = (const float*)d_in[1];
    const float* v  = (const float*)d_in[2];
    const int*   vl = (const int*)d_in[3];
    const float* wq = (const float*)d_in[4];
    const float* wk = (const float*)d_in[5];
    const float* wv = (const float*)d_in[6];
    float* out = (float*)d_out;

    float* qh_s  = (float*)d_ws;                      //  131072 f
    float* kh4   = qh_s  + (size_t)B_*Q_*H_;          //  524288 f
    float* s_prt = kh4   + (size_t)B_*H_*K_;          //   16384 f
    float* o_prt = s_prt + (size_t)B_*Q_*16;          // 8388608 f (32 MB)
    float* psum  = o_prt + (size_t)16*B_*Q_*DV_;      // 2621440 f (10.5 MB)

    proj_part      <<<dim3(640),  dim3(256), 0, stream>>>(q, k, wq, wk, vl, psum);
    proj_reduce    <<<dim3(640),  dim3(256), 0, stream>>>(psum, vl, qh_s, (float4*)kh4);
    attn_part      <<<dim3(2048), dim3(256), 0, stream>>>(qh_s, (const float4*)kh4, wv, vl, v, s_prt, (float4*)o_prt);
    finalize_kernel<<<dim3(512),  dim3(256), 0, stream>>>((const float4*)o_prt, s_prt, vl, (float4*)out);
}